// Round 5
// baseline (313.384 us; speedup 1.0000x reference)
//
#include <hip/hip_runtime.h>
#include <hip/hip_fp16.h>
#include <math.h>

#define BH_N 96
#define S_N 4096
#define D_N 64
#define TOPK 128

typedef unsigned long long ull;

__device__ __forceinline__ ull orderKey(double d) {
  ull u = (ull)__double_as_longlong(d);
  if (u & 0x8000000000000000ULL) u = ~u;
  else u |= 0x8000000000000000ULL;
  return u;  // monotone: a<b (double) <=> orderKey(a)<orderKey(b)
}

// ---------------------------------------------------------------------------
// Kernel A: importance (double mean + std ddof=1) -> u64 orderKey, + zero out.
// HBM roofline carrier: 100 MB read + 100 MB write + 3 MB keys.
// ---------------------------------------------------------------------------
__global__ __launch_bounds__(256)
void imp_zero_kernel(const float* __restrict__ q, float* __restrict__ out,
                     ull* __restrict__ keys) {
  const int tid = threadIdx.x;
  const size_t off = (size_t)blockIdx.x * 1024 + (size_t)tid * 4;
  const float4 v = *reinterpret_cast<const float4*>(q + off);
  float4 z; z.x = z.y = z.z = z.w = 0.f;
  *reinterpret_cast<float4*>(out + off) = z;

  double s  = (double)v.x + (double)v.y + (double)v.z + (double)v.w;
  double ss = (double)v.x * v.x + (double)v.y * v.y +
              (double)v.z * v.z + (double)v.w * v.w;
#pragma unroll
  for (int m = 1; m < 16; m <<= 1) {
    s  += __shfl_xor(s, m, 64);
    ss += __shfl_xor(ss, m, 64);
  }
  if ((tid & 15) == 0) {
    double mean = s * (1.0 / 64.0);
    double var = (ss - s * s * (1.0 / 64.0)) * (1.0 / 63.0);
    if (var < 0.0) var = 0.0;
    keys[(size_t)blockIdx.x * 16 + (tid >> 4)] = orderKey(mean + sqrt(var));
  }
}

// ---------------------------------------------------------------------------
// Fused kernel: per-block radix-256 top-128 select with ORDER-DETERMINISTIC
// emit (s_idx sorted by token index -> identical across the 4 sub-blocks of
// each (b,h)), + attention on a 32-q-row slice.
// 256 threads: rr=tid>>4 -> q-rows {2rr,2rr+1}; cc=tid&15 -> 4 cols per half.
// ---------------------------------------------------------------------------
__global__ __launch_bounds__(256)
void fused_attn_kernel(const float* __restrict__ q, const float* __restrict__ k,
                       const float* __restrict__ v, const ull* __restrict__ keys,
                       float* __restrict__ out) {
  __shared__ int hist[2][256];
  __shared__ int s_idx[TOPK];
  __shared__ int cntG[4][16], cntE[4][16];
  __shared__ int sD, sRem;
  __shared__ __align__(16) float sQ[32 * 68];    // q slice, row-major
  __shared__ __align__(16) float sKT[64 * 68];   // K transposed [kk][r]; reused as V row-major [r][d]
  __shared__ __align__(16) __half sP[32 * 132];  // probabilities

  const int tid = threadIdx.x;
  const int lane = tid & 63;
  const int wv = tid >> 6;
  const int bh = blockIdx.x >> 2;
  const int sub = blockIdx.x & 3;
  const ull* kb = keys + (size_t)bh * S_N;

  // ======== selection phase ========
  ull key[16];
#pragma unroll
  for (int i = 0; i < 16; ++i) key[i] = kb[i * 256 + tid];

  hist[0][tid] = 0;
  hist[1][tid] = 0;
  __syncthreads();

  ull prefix = 0;
  int rem = TOPK;
  int p = 0;
#pragma unroll 1
  for (int b = 0; b < 8; ++b) {
    const int shift = 56 - 8 * b;
    if (b == 0) {
#pragma unroll
      for (int i = 0; i < 16; ++i)
        atomicAdd(&hist[p][(int)((key[i] >> 56) & 255ULL)], 1);
    } else {
#pragma unroll
      for (int i = 0; i < 16; ++i) {
        if (((key[i] ^ prefix) >> (shift + 8)) == 0)
          atomicAdd(&hist[p][(int)((key[i] >> shift) & 255ULL)], 1);
      }
    }
    __syncthreads();
    if (wv == 0) {
      // top-down scan: find digit D where cumulative(from 255) crosses rem
      int rloc = rem;
      for (int c = 0; c < 4; ++c) {
        int d = 255 - (c * 64 + lane);
        int cnt = hist[p][d];
        int pre = cnt;  // inclusive prefix over lanes 0..lane
#pragma unroll
        for (int m = 1; m < 64; m <<= 1) {
          int t = __shfl_up(pre, m, 64);
          if (lane >= m) pre += t;
        }
        int tot = __shfl(pre, 63, 64);
        if (rloc <= tot) {
          ull mask = __ballot(pre >= rloc);
          int l = __ffsll((long long)mask) - 1;
          int preL = __shfl(pre, l, 64);
          int cntL = __shfl(cnt, l, 64);
          if (lane == 0) { sD = 255 - (c * 64 + l); sRem = rloc - (preL - cntL); }
          break;
        }
        rloc -= tot;
      }
    } else {
      // waves 1-3: zero the buffer used next round
      for (int j = tid - 64; j < 256; j += 192) hist[p ^ 1][j] = 0;
    }
    __syncthreads();
    prefix |= ((ull)sD) << shift;
    rem = sRem;
    p ^= 1;
  }
  const ull T = prefix;       // exact 128th-largest key
  const int nselG = TOPK - rem;  // radix invariant: count(key > T) == TOPK - rem

  // ---- deterministic emit: rank by token index via ballot popcounts ----
#pragma unroll
  for (int i = 0; i < 16; ++i) {
    ull bg = __ballot(key[i] > T);
    ull be = __ballot(key[i] == T);
    if (lane == 0) {
      cntG[wv][i] = __popcll(bg);
      cntE[wv][i] = __popcll(be);
    }
  }
  __syncthreads();
  {
    const ull below = (1ULL << lane) - 1ULL;
    int baseG = 0, baseE = 0;
#pragma unroll
    for (int i = 0; i < 16; ++i) {
      ull bg = __ballot(key[i] > T);
      ull be = __ballot(key[i] == T);
      int offG = baseG, offE = baseE;
#pragma unroll
      for (int w = 0; w < 4; ++w) {
        int cg = cntG[w][i], ce = cntE[w][i];
        if (w < wv) { offG += cg; offE += ce; }
        baseG += cg; baseE += ce;
      }
      if (key[i] > T) {
        s_idx[offG + __popcll(bg & below)] = i * 256 + tid;
      } else if (key[i] == T) {
        int tr = offE + __popcll(be & below);  // tie rank by token index
        if (tr < rem) s_idx[nselG + tr] = i * 256 + tid;  // lowest indices first
      }
    }
  }
  __syncthreads();

  // ======== attention phase ========
  const size_t base = (size_t)bh * S_N * D_N;
  const int rgrp = tid >> 4;        // 0..15
  const int c4 = (tid & 15) * 4;    // 0..60
  const int rr = tid >> 4;          // 0..15
  const int cc = tid & 15;          // 0..15

  // gather 32 q rows -> sQ (row-major, stride 68, float4 aligned)
#pragma unroll
  for (int it = 0; it < 2; ++it) {
    int r = it * 16 + rgrp;
    int srow = s_idx[sub * 32 + r];
    float4 val = *reinterpret_cast<const float4*>(q + base + (size_t)srow * D_N + c4);
    *reinterpret_cast<float4*>(&sQ[r * 68 + c4]) = val;
  }

  // QK^T: acc[j][h*4+m] = q-row (2rr+j) x k-slot (h*64 + cc*4 + m)
  float acc[2][8];
#pragma unroll
  for (int j = 0; j < 2; ++j)
#pragma unroll
    for (int m = 0; m < 8; ++m) acc[j][m] = 0.f;

  for (int h = 0; h < 2; ++h) {
    __syncthreads();  // sQ ready (h=0); previous-half sKT reads done (h=1)
    // stage K transposed: sKT[d][r]
#pragma unroll
    for (int it = 0; it < 4; ++it) {
      int r = it * 16 + rgrp;  // 0..63
      int srow = s_idx[h * 64 + r];
      float4 val = *reinterpret_cast<const float4*>(k + base + (size_t)srow * D_N + c4);
      sKT[(c4 + 0) * 68 + r] = val.x;
      sKT[(c4 + 1) * 68 + r] = val.y;
      sKT[(c4 + 2) * 68 + r] = val.z;
      sKT[(c4 + 3) * 68 + r] = val.w;
    }
    __syncthreads();
    for (int kk = 0; kk < 64; ++kk) {
      float q0 = sQ[(2 * rr + 0) * 68 + kk];
      float q1 = sQ[(2 * rr + 1) * 68 + kk];
      float4 kx = *reinterpret_cast<const float4*>(&sKT[kk * 68 + 4 * cc]);
      acc[0][h * 4 + 0] += q0 * kx.x; acc[0][h * 4 + 1] += q0 * kx.y;
      acc[0][h * 4 + 2] += q0 * kx.z; acc[0][h * 4 + 3] += q0 * kx.w;
      acc[1][h * 4 + 0] += q1 * kx.x; acc[1][h * 4 + 1] += q1 * kx.y;
      acc[1][h * 4 + 2] += q1 * kx.z; acc[1][h * 4 + 3] += q1 * kx.w;
    }
  }

  // softmax over rows 2rr, 2rr+1 (reduce across the 16 consecutive cc lanes)
  float rmax[2], rsum[2];
#pragma unroll
  for (int j = 0; j < 2; ++j) {
    float mx = acc[j][0];
#pragma unroll
    for (int m = 1; m < 8; ++m) mx = fmaxf(mx, acc[j][m]);
    rmax[j] = mx;
  }
#pragma unroll
  for (int mm = 1; mm < 16; mm <<= 1)
#pragma unroll
    for (int j = 0; j < 2; ++j) rmax[j] = fmaxf(rmax[j], __shfl_xor(rmax[j], mm, 64));
#pragma unroll
  for (int j = 0; j < 2; ++j) {
    float sum = 0.f;
#pragma unroll
    for (int m = 0; m < 8; ++m) {
      float pe = __expf(0.125f * (acc[j][m] - rmax[j]));  // scale 1/sqrt(64)
      acc[j][m] = pe;
      sum += pe;
    }
    rsum[j] = sum;
  }
#pragma unroll
  for (int mm = 1; mm < 16; mm <<= 1)
#pragma unroll
    for (int j = 0; j < 2; ++j) rsum[j] += __shfl_xor(rsum[j], mm, 64);
#pragma unroll
  for (int j = 0; j < 2; ++j) {
    float rinv = 1.f / rsum[j];
#pragma unroll
    for (int h2 = 0; h2 < 2; ++h2)
#pragma unroll
      for (int m = 0; m < 4; ++m) {
        int col = h2 * 64 + cc * 4 + m;
        sP[(2 * rr + j) * 132 + col] = __float2half_rn(acc[j][h2 * 4 + m] * rinv);
      }
  }

  // PV: acc2[j][m] = out row (2rr+j), d-col (cc*4+m).  sV aliases sKT.
  float* sV = sKT;
  float acc2[2][4];
#pragma unroll
  for (int j = 0; j < 2; ++j)
#pragma unroll
    for (int m = 0; m < 4; ++m) acc2[j][m] = 0.f;

  for (int h = 0; h < 2; ++h) {
    __syncthreads();  // h=0: sP writes + QK sKT reads done; h=1: half0 sV reads done
#pragma unroll
    for (int it = 0; it < 4; ++it) {
      int r = it * 16 + rgrp;
      int srow = s_idx[h * 64 + r];
      float4 val = *reinterpret_cast<const float4*>(v + base + (size_t)srow * D_N + c4);
      *reinterpret_cast<float4*>(&sV[r * 68 + c4]) = val;
    }
    __syncthreads();
    for (int s2 = 0; s2 < 64; ++s2) {
      int scol = h * 64 + s2;
      float p0 = __half2float(sP[(2 * rr + 0) * 132 + scol]);
      float p1 = __half2float(sP[(2 * rr + 1) * 132 + scol]);
      float4 vv = *reinterpret_cast<const float4*>(&sV[s2 * 68 + 4 * cc]);
      acc2[0][0] += p0 * vv.x; acc2[0][1] += p0 * vv.y;
      acc2[0][2] += p0 * vv.z; acc2[0][3] += p0 * vv.w;
      acc2[1][0] += p1 * vv.x; acc2[1][1] += p1 * vv.y;
      acc2[1][2] += p1 * vv.z; acc2[1][3] += p1 * vv.w;
    }
  }

  // scatter (out zeroed by kernel A)
#pragma unroll
  for (int j = 0; j < 2; ++j) {
    int srow = s_idx[sub * 32 + 2 * rr + j];
    float4 val;
    val.x = acc2[j][0]; val.y = acc2[j][1]; val.z = acc2[j][2]; val.w = acc2[j][3];
    *reinterpret_cast<float4*>(out + base + (size_t)srow * D_N + 4 * cc) = val;
  }
}

extern "C" void kernel_launch(void* const* d_in, const int* in_sizes, int n_in,
                              void* d_out, int out_size, void* d_ws, size_t ws_size,
                              hipStream_t stream) {
  const float* q = (const float*)d_in[0];
  const float* k = (const float*)d_in[1];
  const float* v = (const float*)d_in[2];
  float* out = (float*)d_out;
  ull* keys = (ull*)d_ws;  // 96*4096*8 = 3 MB

  imp_zero_kernel<<<24576, 256, 0, stream>>>(q, out, keys);
  fused_attn_kernel<<<BH_N * 4, 256, 0, stream>>>(q, k, v, keys, out);
}